// Round 9
// baseline (430.501 us; speedup 1.0000x reference)
//
#include <hip/hip_runtime.h>

// fp32 in/out; bf16 MFMA pipeline (threshold = 2% of ref absmax).
//
// Pipeline (4 launches in merged mode):
//  1) prep : blocks [0,6144)    : cvt X|Wi|Wd -> bf16
//            blocks [6144,6400) : cvtT (out_w -> bf16 transposed)
//            blocks [6400,6656) : bck (bc = Wd@bo + bd, dep scores)
//  2) gemm_qkv : Q,K cols -> qkv bf16; V cols -> Vt DIRECTLY (transposed,
//     zero-shuffle key permutation). XCD-swizzled grid. Blocks >=1536:
//     Wc = Wdb @ WoTb^T concurrently.
//  3) attn : flash attention, ZERO-LDS: K/V fragments loaded direct to
//     registers from L2 (XCD-grouped decode keeps K/V L2-resident, proven
//     R6: FETCH 139->25MB). No barriers, no ds_read -> the per-kt latency
//     chain loses the LDS round-trip; waves free-run with K prefetched one
//     tile ahead (reg double-buffer) and V single-buffered at full-loop
//     WAR distance. 1-wave blocks (64 thr), grid 2048.
//  4) gemm_fin : enh = ctx @ Wc^T + bc (fp32 -> d_out+4), XCD-swizzled.
//
// R9 note: resubmission of R8 (container-level failure, audited clean —
// same flake class as R4->R5 which passed unchanged).

typedef __attribute__((ext_vector_type(8))) short short8;   // 8 x bf16
typedef __attribute__((ext_vector_type(4))) float float4v;  // MFMA C/D frag
typedef __attribute__((ext_vector_type(4))) int int4v;      // 16B copy
typedef __attribute__((ext_vector_type(2))) unsigned uint2v;

__device__ inline ushort f2bf(float f) {
  union { float f; unsigned u; } v; v.f = f;
  unsigned u = v.u;
  return (ushort)((u + 0x7FFFu + ((u >> 16) & 1u)) >> 16);  // RNE
}
__device__ inline float bf2f(ushort h) {
  union { unsigned u; float f; } v; v.u = ((unsigned)h) << 16;
  return v.f;
}
// Single-instruction RNE pack of two floats to bf16x2 (lo -> low half).
__device__ inline unsigned cvtpk(float lo, float hi) {
  unsigned r;
  asm("v_cvt_pk_bf16_f32 %0, %1, %2" : "=v"(r) : "v"(lo), "v"(hi));
  return r;
}

// ---------------------------------------------------------------------------
// prep: fused elementwise cvt + transposed cvt + bias precompute.
// ---------------------------------------------------------------------------
__global__ __launch_bounds__(256)
void prep(const float* __restrict__ X, const float* __restrict__ Wi,
          const float* __restrict__ Wd, const float* __restrict__ Wo,
          const float* __restrict__ bo, const float* __restrict__ bd,
          ushort* __restrict__ Xb, ushort* __restrict__ Wib,
          ushort* __restrict__ Wdb, ushort* __restrict__ WoT,
          float* __restrict__ bc, float* __restrict__ dep) {
  __shared__ ushort Ts[64 * 72];
  const int bid = blockIdx.x;
  const int t = threadIdx.x;

  if (bid < 6144) {
    size_t i = ((size_t)bid * 256 + t) * 8;
    const float* src; ushort* dst;
    if (i < 8388608)        { src = X  + i;              dst = Xb  + i; }
    else if (i < 11534336)  { src = Wi + (i - 8388608);  dst = Wib + (i - 8388608); }
    else                    { src = Wd + (i - 11534336); dst = Wdb + (i - 11534336); }
    float4v a = *(const float4v*)(src);
    float4v b = *(const float4v*)(src + 4);
    ushort o[8];
    o[0] = f2bf(a.x); o[1] = f2bf(a.y); o[2] = f2bf(a.z); o[3] = f2bf(a.w);
    o[4] = f2bf(b.x); o[5] = f2bf(b.y); o[6] = f2bf(b.z); o[7] = f2bf(b.w);
    *(int4v*)dst = *(const int4v*)o;
  } else if (bid < 6400) {
    const int q = bid - 6144;
    const int ct = (q & 15) * 64, rt = (q >> 4) * 64;
#pragma unroll
    for (int i = 0; i < 4; i++) {
      const int row = i * 16 + (t >> 4), col4 = (t & 15) * 4;
      float4v v = *(const float4v*)(Wo + (size_t)(rt + row) * 1024 + ct + col4);
      ushort o[4] = {f2bf(v.x), f2bf(v.y), f2bf(v.z), f2bf(v.w)};
      *(uint2v*)(Ts + row * 72 + col4) = *(const uint2v*)o;
    }
    __syncthreads();
#pragma unroll
    for (int it = 0; it < 2; it++) {
      const int c = it * 256 + t;
      const int oc = c >> 3, r8 = (c & 7) * 8;
      ushort o[8];
#pragma unroll
      for (int j = 0; j < 8; j++) o[j] = Ts[(r8 + j) * 72 + oc];
      *(int4v*)(WoT + (size_t)(ct + oc) * 1024 + rt + r8) = *(const int4v*)o;
    }
  } else {
    const int w = t >> 6, lane = t & 63;
    const int row = (bid - 6400) * 4 + w;
    float s = 0.f;
#pragma unroll
    for (int i = 0; i < 4; i++) {
      const int j = i * 256 + lane * 4;
      float4v wv = *(const float4v*)(Wd + (size_t)row * 1024 + j);
      float4v bv = *(const float4v*)(bo + j);
      s += wv.x * bv.x + wv.y * bv.y + wv.z * bv.z + wv.w * bv.w;
    }
#pragma unroll
    for (int off = 1; off <= 32; off <<= 1) s += __shfl_xor(s, off);
    if (lane == 0) bc[row] = s + bd[row];
    if (row < 4 && lane == 1) dep[row] = 1.0f / 2048.0f;  // softmax rows sum to 1
  }
}

// ---------------------------------------------------------------------------
// Generic GEMM (fallback Wc path): C = A @ W^T, bf16 out. 128x128, BK=32.
// ---------------------------------------------------------------------------
__global__ __launch_bounds__(256, 2)
void gemm_bt(const ushort* __restrict__ A, const ushort* __restrict__ W,
             ushort* __restrict__ C, int K) {
  __shared__ ushort As[128 * 32];
  __shared__ ushort Bs[128 * 32];
  const int t = threadIdx.x;
  const int w = t >> 6;
  const int lane = t & 63;
  const int m16 = lane & 15, quad = lane >> 4;
  const int bx = blockIdx.x, by = blockIdx.y;
  const int warpRow = w >> 1, warpCol = w & 1;

  const int srow = t >> 2;
  const int scol = (t & 3) * 8;
  const ushort* Aptr = A + (size_t)(by * 128) * K;
  const ushort* Wptr = W + (size_t)(bx * 128) * K;

  float4v zero4 = {0.f, 0.f, 0.f, 0.f};
  float4v acc[4][4];
#pragma unroll
  for (int i = 0; i < 4; i++)
#pragma unroll
    for (int j = 0; j < 4; j++) acc[i][j] = zero4;

  for (int k0 = 0; k0 < K; k0 += 32) {
    __syncthreads();
#pragma unroll
    for (int r = 0; r < 2; r++) {
      const ushort* g = Aptr + (size_t)(r * 64 + srow) * K + (k0 + scol);
      __builtin_amdgcn_global_load_lds(
          (const __attribute__((address_space(1))) void*)g,
          (__attribute__((address_space(3))) void*)(As + r * 2048 + t * 8),
          16, 0, 0);
    }
#pragma unroll
    for (int r = 0; r < 2; r++) {
      const ushort* g = Wptr + (size_t)(r * 64 + srow) * K + (k0 + scol);
      __builtin_amdgcn_global_load_lds(
          (const __attribute__((address_space(1))) void*)g,
          (__attribute__((address_space(3))) void*)(Bs + r * 2048 + t * 8),
          16, 0, 0);
    }
    __syncthreads();

    short8 af[4], bf[4];
#pragma unroll
    for (int i = 0; i < 4; i++) {
      af[i] = *(const short8*)(As + (warpRow * 64 + i * 16 + m16) * 32 + quad * 8);
      bf[i] = *(const short8*)(Bs + (warpCol * 64 + i * 16 + m16) * 32 + quad * 8);
    }
#pragma unroll
    for (int i = 0; i < 4; i++)
#pragma unroll
      for (int j = 0; j < 4; j++)
        acc[i][j] = __builtin_amdgcn_mfma_f32_16x16x32_bf16(af[i], bf[j],
                                                            acc[i][j], 0, 0, 0);
  }

  const int crow_base = by * 128 + warpRow * 64;
  const int ccol_base = bx * 128 + warpCol * 64;
#pragma unroll
  for (int j = 0; j < 4; j++) {
    const int col = ccol_base + j * 16 + m16;
#pragma unroll
    for (int i = 0; i < 4; i++) {
      const int row = crow_base + i * 16 + quad * 4;
#pragma unroll
      for (int r = 0; r < 4; r++)
        C[(size_t)(row + r) * 1024 + col] = f2bf(acc[i][j][r]);
    }
  }
}

// ---------------------------------------------------------------------------
// Fused QKV GEMM, XCD-swizzled. Blocks < 1536: qkv = Xb @ Wib^T + bi.
//   - bx < 16 : Q,K columns -> qkv (bf16, stride 3072)
//   - bx >= 16: V columns   -> Vt transposed + zero-shuffle key permutation
// Blocks >= 1536 (merged mode): Wc = A2 @ W2^T (bf16) -> C2.
// ---------------------------------------------------------------------------
__global__ __launch_bounds__(256, 2)
void gemm_qkv(const ushort* __restrict__ Xb, const ushort* __restrict__ Wib,
              const float* __restrict__ bi, ushort* __restrict__ qkv,
              ushort* __restrict__ Vt,
              const ushort* __restrict__ A2, const ushort* __restrict__ W2,
              ushort* __restrict__ C2) {
  __shared__ ushort As[128 * 32];
  __shared__ ushort Bs[128 * 32];
  const int t = threadIdx.x;
  const int w = t >> 6;
  const int lane = t & 63;
  const int m16 = lane & 15, quad = lane >> 4;
  const int bid = blockIdx.x;
  const bool second = bid >= 1536;
  int bx, by;
  const ushort *A, *W;
  if (!second) {
    const int swz = (bid & 7) * 192 + (bid >> 3);   // XCD-contiguous panels
    bx = swz % 24; by = swz / 24; A = Xb; W = Wib;
  } else {
    const int b2 = bid - 1536; bx = b2 & 7; by = b2 >> 3; A = A2; W = W2;
  }
  const int warpRow = w >> 1, warpCol = w & 1;
  const int K = 1024;

  const int srow = t >> 2;
  const int scol = (t & 3) * 8;
  const ushort* Aptr = A + (size_t)(by * 128) * K;
  const ushort* Wptr = W + (size_t)(bx * 128) * K;

  float4v zero4 = {0.f, 0.f, 0.f, 0.f};
  float4v acc[4][4];
#pragma unroll
  for (int i = 0; i < 4; i++)
#pragma unroll
    for (int j = 0; j < 4; j++) acc[i][j] = zero4;

  for (int k0 = 0; k0 < K; k0 += 32) {
    __syncthreads();
#pragma unroll
    for (int r = 0; r < 2; r++) {
      const ushort* g = Aptr + (size_t)(r * 64 + srow) * K + (k0 + scol);
      __builtin_amdgcn_global_load_lds(
          (const __attribute__((address_space(1))) void*)g,
          (__attribute__((address_space(3))) void*)(As + r * 2048 + t * 8),
          16, 0, 0);
    }
#pragma unroll
    for (int r = 0; r < 2; r++) {
      const ushort* g = Wptr + (size_t)(r * 64 + srow) * K + (k0 + scol);
      __builtin_amdgcn_global_load_lds(
          (const __attribute__((address_space(1))) void*)g,
          (__attribute__((address_space(3))) void*)(Bs + r * 2048 + t * 8),
          16, 0, 0);
    }
    __syncthreads();

    short8 af[4], bf[4];
#pragma unroll
    for (int i = 0; i < 4; i++) {
      af[i] = *(const short8*)(As + (warpRow * 64 + i * 16 + m16) * 32 + quad * 8);
      bf[i] = *(const short8*)(Bs + (warpCol * 64 + i * 16 + m16) * 32 + quad * 8);
    }
#pragma unroll
    for (int i = 0; i < 4; i++)
#pragma unroll
      for (int j = 0; j < 4; j++)
        acc[i][j] = __builtin_amdgcn_mfma_f32_16x16x32_bf16(af[i], bf[j],
                                                            acc[i][j], 0, 0, 0);
  }

  const int crow_base = by * 128 + warpRow * 64;
  const int ccol_base = bx * 128 + warpCol * 64;

  if (second) {
#pragma unroll
    for (int j = 0; j < 4; j++) {
      const int col = ccol_base + j * 16 + m16;
#pragma unroll
      for (int i = 0; i < 4; i++) {
        const int row = crow_base + i * 16 + quad * 4;
#pragma unroll
        for (int r = 0; r < 4; r++)
          C2[(size_t)(row + r) * 1024 + col] = f2bf(acc[i][j][r]);
      }
    }
  } else if (bx < 16) {
#pragma unroll
    for (int j = 0; j < 4; j++) {
      const int col = ccol_base + j * 16 + m16;
      const float bv = bi[col];
#pragma unroll
      for (int i = 0; i < 4; i++) {
        const int row = crow_base + i * 16 + quad * 4;
#pragma unroll
        for (int r = 0; r < 4; r++)
          qkv[(size_t)(row + r) * 3072 + col] = f2bf(acc[i][j][r] + bv);
      }
    }
  } else {
    // V columns -> Vt transposed + key-permuted.
    const int b = by >> 4;
#pragma unroll
    for (int j = 0; j < 4; j++) {
      const int col = ccol_base + j * 16 + m16;   // 2048..3071
      const float bv = bi[col];
      const int vcol = col - 2048;
      const int h = vcol >> 7, d = vcol & 127;
      ushort* vrow = Vt + (size_t)((b * 8 + h) * 128 + d) * 2048;
#pragma unroll
      for (int i = 0; i < 4; i++) {
        const int pos = ((by & 15) << 7) + warpRow * 64 + ((i >> 1) << 5) +
                        (2 * quad + (i & 1)) * 4;
        uint2v o;
        o.x = cvtpk(acc[i][j][0] + bv, acc[i][j][1] + bv);
        o.y = cvtpk(acc[i][j][2] + bv, acc[i][j][3] + bv);
        *(uint2v*)(vrow + pos) = o;
      }
    }
  }
}

// ---------------------------------------------------------------------------
// Flash attention, ZERO-LDS. 64 thr = 1 wave, 32 q/wave; grid 2048.
// XCD-grouped decode (block->XCD = id%8): XCD x owns (h,b) pairs 4x..4x+3;
// the 64 q-waves of one pair read that pair's K/V (1MB) from the XCD's L2
// (4 pairs = 4MB working set) [FETCH 139->25MB proven R6].
// K/V fragments load DIRECT to VGPRs (16B/lane, 16 lines/instr, 4 lanes/line,
// 100% byte efficiency). K reg-double-buffered one kt ahead; V single-
// buffered, issued right after its last PV read (full-loop WAR distance).
// No barriers, no ds_read: the kt chain is MFMA -> exp2/pack -> MFMA with
// loads overlapped via compiler-counted vmcnt. Epilogue transpose via shfl.
// S^T = K.Q^T, lane-local softmax, zero-shuffle PV (Vt key-permuted).
// #pragma unroll 2 on the kt loop keeps kf[cur] statically indexed (rule #20).
// ---------------------------------------------------------------------------
__global__ __launch_bounds__(64, 2)
void attn(const ushort* __restrict__ qkv, const ushort* __restrict__ Vt,
          ushort* __restrict__ ctx) {
  const int lane = threadIdx.x;
  const int m16 = lane & 15, quad = lane >> 4;
  const int i = blockIdx.x;
  const int x = i & 7, j0 = i >> 3;          // x = XCD
  const int pair = x * 4 + (j0 >> 6);        // 4 (h,b) pairs per XCD
  const int qw = j0 & 63;                    // q-wave within pair (32 q each)
  const int h = pair & 7, b = pair >> 3;
  const int E3 = 3072;
  const size_t bbase = (size_t)b * 2048;

  const ushort* Qg = qkv + (bbase + qw * 32) * E3 + h * 128;
  const ushort* Kg = qkv + bbase * E3 + 1024 + h * 128;
  const ushort* Vg = Vt + (size_t)((b * 8 + h) * 128) * 2048;

  // Per-lane fragment loads (direct global -> VGPR, 16B each):
  //  K frag (mt2,ks): K[kt*32 + mt2*16 + m16][ks*32 + quad*8 .. +7]
  //  V frag (dt)    : Vt-row d=dt*16+m16, permuted keys kt*32 + quad*8 .. +7
  auto loadK = [&](int kt, short8* kf) {
#pragma unroll
    for (int mt2 = 0; mt2 < 2; mt2++)
#pragma unroll
      for (int ks = 0; ks < 4; ks++)
        kf[mt2 * 4 + ks] = *(const short8*)(
            Kg + (size_t)(kt * 32 + mt2 * 16 + m16) * E3 + ks * 32 + quad * 8);
  };
  auto loadV = [&](int kt, short8* vf) {
#pragma unroll
    for (int dt = 0; dt < 8; dt++)
      vf[dt] = *(const short8*)(
          Vg + (size_t)(dt * 16 + m16) * 2048 + kt * 32 + quad * 8);
  };

  const float c1 = 0.08838834764831845f * 1.4426950408889634f;  // scale*log2e
  // Q B-frags (n=m16 query, k=quad*8+j), pre-scaled by c1.
  short8 qf[2][4];
#pragma unroll
  for (int g = 0; g < 2; g++)
#pragma unroll
    for (int ks = 0; ks < 4; ks++) {
      short8 raw = *(const short8*)(Qg + (size_t)(g * 16 + m16) * E3 + ks * 32 + quad * 8);
      short8 s;
#pragma unroll
      for (int jj = 0; jj < 8; jj++) s[jj] = (short)f2bf(bf2f((ushort)raw[jj]) * c1);
      qf[g][ks] = s;
    }

  short8 kf[2][8];   // K double-buffer (prefetch 1 kt ahead)
  short8 vfr[8];     // V single-buffer (full-loop WAR distance)
  loadK(0, kf[0]);
  loadV(0, vfr);

  float4v zero4 = {0.f, 0.f, 0.f, 0.f};
  float4v Oacc[2][8];
#pragma unroll
  for (int g = 0; g < 2; g++)
#pragma unroll
    for (int dt = 0; dt < 8; dt++) Oacc[g][dt] = zero4;
  float lsum[2] = {0.f, 0.f};

#pragma unroll 2
  for (int kt = 0; kt < 64; kt++) {
    const int cur = kt & 1;

    // ---- QK^T: 16 MFMA from kf[cur] ----
    float4v st[2][2];  // [g][mt2: key-16-group]
    st[0][0] = zero4; st[0][1] = zero4; st[1][0] = zero4; st[1][1] = zero4;
    __builtin_amdgcn_s_setprio(1);
#pragma unroll
    for (int ks = 0; ks < 4; ks++) {
#pragma unroll
      for (int mt2 = 0; mt2 < 2; mt2++) {
        st[0][mt2] = __builtin_amdgcn_mfma_f32_16x16x32_bf16(
            kf[cur][mt2 * 4 + ks], qf[0][ks], st[0][mt2], 0, 0, 0);
        st[1][mt2] = __builtin_amdgcn_mfma_f32_16x16x32_bf16(
            kf[cur][mt2 * 4 + ks], qf[1][ks], st[1][mt2], 0, 0, 0);
      }
    }
    __builtin_amdgcn_s_setprio(0);
    // prefetch K for kt+1 (overlaps softmax + PV + next-QK wait)
    if (kt < 63) loadK(kt + 1, kf[cur ^ 1]);

    // ---- softmax (lane-local; this tile's keys live in this lane) ----
    short8 pfr[2];
#pragma unroll
    for (int g = 0; g < 2; g++) {
      unsigned pk[4];
#pragma unroll
      for (int mt2 = 0; mt2 < 2; mt2++) {
        float p0 = __builtin_exp2f(st[g][mt2][0]);
        float p1 = __builtin_exp2f(st[g][mt2][1]);
        float p2 = __builtin_exp2f(st[g][mt2][2]);
        float p3 = __builtin_exp2f(st[g][mt2][3]);
        lsum[g] += (p0 + p1) + (p2 + p3);
        pk[mt2 * 2]     = cvtpk(p0, p1);
        pk[mt2 * 2 + 1] = cvtpk(p2, p3);
      }
      union { int4v iv; short8 s; } pf;
      pf.iv.x = (int)pk[0];
      pf.iv.y = (int)pk[1];
      pf.iv.z = (int)pk[2];
      pf.iv.w = (int)pk[3];
      pfr[g] = pf.s;
    }

    // ---- PV: 16 MFMA from vfr ----
    __builtin_amdgcn_s_setprio(1);
#pragma unroll
    for (int dt = 0; dt < 8; dt++) {
      Oacc[0][dt] = __builtin_amdgcn_mfma_f32_16x16x32_bf16(pfr[0], vfr[dt], Oacc[0][dt], 0, 0, 0);
      Oacc[1][dt] = __builtin_amdgcn_mfma_f32_16x16x32_bf16(pfr[1], vfr[dt], Oacc[1][dt], 0, 0, 0);
    }
    __builtin_amdgcn_s_setprio(0);
    // reload V for kt+1 (WAR after PV reads; covers next QK + softmax)
    if (kt < 63) loadV(kt + 1, vfr);
  }

  // Epilogue: l(q=m16) after quad-reduce; fetch l(q=quad*4+r) via shfl.
#pragma unroll
  for (int g = 0; g < 2; g++) {
    float l = lsum[g];
    l += __shfl_xor(l, 16);
    l += __shfl_xor(l, 32);
    float linv[4];
#pragma unroll
    for (int r = 0; r < 4; r++) linv[r] = 1.0f / __shfl(l, quad * 4 + r);
#pragma unroll
    for (int r = 0; r < 4; r++) {
      const int row = qw * 32 + g * 16 + quad * 4 + r;
      ushort* crow = ctx + (bbase + row) * 1024 + h * 128;
#pragma unroll
      for (int dt = 0; dt < 8; dt++)
        crow[dt * 16 + m16] = f2bf(Oacc[g][dt][r] * linv[r]);
    }
  }
}

// ---------------------------------------------------------------------------
// Final GEMM: out = ctx[8192,1024] @ Wc[1024,1024]^T + bc, fp32 out.
// XCD-swizzled: per XCD 8 contiguous by-panels (2MB A, L2-resident).
// ---------------------------------------------------------------------------
__global__ __launch_bounds__(256, 2)
void gemm_fin(const ushort* __restrict__ A, const ushort* __restrict__ W,
              const float* __restrict__ bias, float* __restrict__ C) {
  __shared__ ushort As[128 * 32];
  __shared__ ushort Bs[128 * 32];
  const int t = threadIdx.x;
  const int w = t >> 6;
  const int lane = t & 63;
  const int m16 = lane & 15, quad = lane >> 4;
  const int swz = (blockIdx.x & 7) * 64 + (blockIdx.x >> 3);
  const int bx = swz & 7, by = swz >> 3;
  const int warpRow = w >> 1, warpCol = w & 1;
  const int K = 1024;

  const int srow = t >> 2;
  const int scol = (t & 3) * 8;
  const ushort* Aptr = A + (size_t)(by * 128) * K;
  const ushort* Wptr = W + (size_t)(bx * 128) * K;

  float4v zero4 = {0.f, 0.f, 0.f, 0.f};
  float4v acc[4][4];
#pragma unroll
  for (int i = 0; i < 4; i++)
#pragma unroll
    for (int j = 0; j < 4; j++) acc[i][j] = zero4;

  for (int k0 = 0; k0 < K; k0 += 32) {
    __syncthreads();
#pragma unroll
    for (int r = 0; r < 2; r++) {
      const ushort* g = Aptr + (size_t)(r * 64 + srow) * K + (k0 + scol);
      __builtin_amdgcn_global_load_lds(
          (const __attribute__((address_space(1))) void*)g,
          (__attribute__((address_space(3))) void*)(As + r * 2048 + t * 8),
          16, 0, 0);
    }
#pragma unroll
    for (int r = 0; r < 2; r++) {
      const ushort* g = Wptr + (size_t)(r * 64 + srow) * K + (k0 + scol);
      __builtin_amdgcn_global_load_lds(
          (const __attribute__((address_space(1))) void*)g,
          (__attribute__((address_space(3))) void*)(Bs + r * 2048 + t * 8),
          16, 0, 0);
    }
    __syncthreads();

    short8 af[4], bf[4];
#pragma unroll
    for (int i = 0; i < 4; i++) {
      af[i] = *(const short8*)(As + (warpRow * 64 + i * 16 + m16) * 32 + quad * 8);
      bf[i] = *(const short8*)(Bs + (warpCol * 64 + i * 16 + m16) * 32 + quad * 8);
    }
#pragma unroll
    for (int i = 0; i < 4; i++)
#pragma unroll
      for (int j = 0; j < 4; j++)
        acc[i][j] = __builtin_amdgcn_mfma_f32_16x16x32_bf16(af[i], bf[j],
                                                            acc[i][j], 0, 0, 0);
  }

  const int crow_base = by * 128 + warpRow * 64;
  const int ccol_base = bx * 128 + warpCol * 64;
#pragma unroll
  for (int j = 0; j < 4; j++) {
    const int col = ccol_base + j * 16 + m16;
    const float bv = bias[col];
#pragma unroll
    for (int i = 0; i < 4; i++) {
      const int row = crow_base + i * 16 + quad * 4;
#pragma unroll
      for (int r = 0; r < 4; r++)
        C[(size_t)(row + r) * 1024 + col] = acc[i][j][r] + bv;
    }
  }
}

extern "C" void kernel_launch(void* const* d_in, const int* in_sizes, int n_in,
                              void* d_out, int out_size, void* d_ws, size_t ws_size,
                              hipStream_t stream) {
  const float* X  = (const float*)d_in[0];
  const float* Wi = (const float*)d_in[1];
  const float* bi = (const float*)d_in[2];
  const float* Wo = (const float*)d_in[3];
  const float* bo = (const float*)d_in[4];
  const float* Wd = (const float*)d_in[5];
  const float* bd = (const float*)d_in[6];
  float* out = (float*)d_out;

  ushort* p    = (ushort*)d_ws;
  ushort* Xb   = p; p += (size_t)8192 * 1024;   // 16.8MB; ctx reuses (post-qkv)
  ushort* Wib  = p; p += (size_t)3072 * 1024;   //  6.3MB
  ushort* WoTb = p; p += (size_t)1024 * 1024;   //  2.1MB
  ushort* Wdb  = p; p += (size_t)1024 * 1024;   //  2.1MB
  ushort* qkv  = p; p += (size_t)8192 * 3072;   // 50.3MB (V cols unused)
  ushort* Vt   = p; p += (size_t)4096 * 2048;   // 16.8MB
  float*  bc   = (float*)p; p += 2048;          //  4KB
  ushort* WcbSep = p; p += (size_t)1024 * 1024; //  2.1MB (merged mode only)
  const size_t need_merged = (size_t)((char*)p - (char*)d_ws);
  const bool merged = ws_size >= need_merged;

  ushort* ctx = Xb;                     // free after qkv GEMM consumed Xb
  ushort* Wcb = merged ? WcbSep : Wib;  // fallback: alias (separate launch)

  prep<<<6656, 256, 0, stream>>>(X, Wi, Wd, Wo, bo, bd,
                                 Xb, Wib, Wdb, WoTb, bc, out);
  if (merged) {
    gemm_qkv<<<1600, 256, 0, stream>>>(Xb, Wib, bi, qkv, Vt, Wdb, WoTb, Wcb);
  } else {
    gemm_qkv<<<1536, 256, 0, stream>>>(Xb, Wib, bi, qkv, Vt, Wdb, WoTb, nullptr);
    gemm_bt<<<dim3(8, 8), 256, 0, stream>>>(Wdb, WoTb, Wcb, 1024);
  }
  attn<<<2048, 64, 0, stream>>>(qkv, Vt, ctx);
  gemm_fin<<<512, 256, 0, stream>>>(ctx, Wcb, bc, out + 4);
}

// Round 10
// 283.918 us; speedup vs baseline: 1.5163x; 1.5163x over previous
//
#include <hip/hip_runtime.h>

// fp32 in/out; bf16 MFMA pipeline (threshold = 2% of ref absmax).
//
// Pipeline (4 launches in merged mode):
//  1) prep : blocks [0,6144)    : cvt X|Wi|Wd -> bf16
//            blocks [6144,6400) : cvtT (out_w -> bf16 transposed)
//            blocks [6400,6656) : bck (bc = Wd@bo + bd, dep scores)
//  2) gemm_qkv : Q,K cols -> qkv bf16; V cols -> Vt DIRECTLY (transposed,
//     zero-shuffle key permutation). XCD-swizzled grid. Blocks >=1536:
//     Wc = Wdb @ WoTb^T concurrently.
//  3) attn : flash attention, R5 structure (best measured: 96.6us): 4 waves,
//     32 q/wave, KVBLK=32, 4-deep LDS ring, counted vmcnt; PLUS R6's
//     XCD-grouped decode (1-D grid, block->XCD = id%8; each XCD owns 4
//     (h,b) pairs -> K/V L2-resident, FETCH 139->25MB proven).
//     R9 lesson: zero-LDS direct-to-reg was 2.6x WORSE (251us) -- per-wave
//     L2 amplification ~3.2GB + compiler sinks loads (VGPR 120, no dbuf).
//     LDS staging is structural; ~97us is this design's plateau.
//  4) gemm_fin : enh = ctx @ Wc^T + bc (fp32 -> d_out+4), XCD-swizzled.

typedef __attribute__((ext_vector_type(8))) short short8;   // 8 x bf16
typedef __attribute__((ext_vector_type(4))) float float4v;  // MFMA C/D frag
typedef __attribute__((ext_vector_type(4))) int int4v;      // 16B copy
typedef __attribute__((ext_vector_type(2))) unsigned uint2v;

__device__ inline ushort f2bf(float f) {
  union { float f; unsigned u; } v; v.f = f;
  unsigned u = v.u;
  return (ushort)((u + 0x7FFFu + ((u >> 16) & 1u)) >> 16);  // RNE
}
__device__ inline float bf2f(ushort h) {
  union { unsigned u; float f; } v; v.u = ((unsigned)h) << 16;
  return v.f;
}
// Single-instruction RNE pack of two floats to bf16x2 (lo -> low half).
__device__ inline unsigned cvtpk(float lo, float hi) {
  unsigned r;
  asm("v_cvt_pk_bf16_f32 %0, %1, %2" : "=v"(r) : "v"(lo), "v"(hi));
  return r;
}

// ---------------------------------------------------------------------------
// prep: fused elementwise cvt + transposed cvt + bias precompute.
// ---------------------------------------------------------------------------
__global__ __launch_bounds__(256)
void prep(const float* __restrict__ X, const float* __restrict__ Wi,
          const float* __restrict__ Wd, const float* __restrict__ Wo,
          const float* __restrict__ bo, const float* __restrict__ bd,
          ushort* __restrict__ Xb, ushort* __restrict__ Wib,
          ushort* __restrict__ Wdb, ushort* __restrict__ WoT,
          float* __restrict__ bc, float* __restrict__ dep) {
  __shared__ ushort Ts[64 * 72];
  const int bid = blockIdx.x;
  const int t = threadIdx.x;

  if (bid < 6144) {
    size_t i = ((size_t)bid * 256 + t) * 8;
    const float* src; ushort* dst;
    if (i < 8388608)        { src = X  + i;              dst = Xb  + i; }
    else if (i < 11534336)  { src = Wi + (i - 8388608);  dst = Wib + (i - 8388608); }
    else                    { src = Wd + (i - 11534336); dst = Wdb + (i - 11534336); }
    float4v a = *(const float4v*)(src);
    float4v b = *(const float4v*)(src + 4);
    ushort o[8];
    o[0] = f2bf(a.x); o[1] = f2bf(a.y); o[2] = f2bf(a.z); o[3] = f2bf(a.w);
    o[4] = f2bf(b.x); o[5] = f2bf(b.y); o[6] = f2bf(b.z); o[7] = f2bf(b.w);
    *(int4v*)dst = *(const int4v*)o;
  } else if (bid < 6400) {
    const int q = bid - 6144;
    const int ct = (q & 15) * 64, rt = (q >> 4) * 64;
#pragma unroll
    for (int i = 0; i < 4; i++) {
      const int row = i * 16 + (t >> 4), col4 = (t & 15) * 4;
      float4v v = *(const float4v*)(Wo + (size_t)(rt + row) * 1024 + ct + col4);
      ushort o[4] = {f2bf(v.x), f2bf(v.y), f2bf(v.z), f2bf(v.w)};
      *(uint2v*)(Ts + row * 72 + col4) = *(const uint2v*)o;
    }
    __syncthreads();
#pragma unroll
    for (int it = 0; it < 2; it++) {
      const int c = it * 256 + t;
      const int oc = c >> 3, r8 = (c & 7) * 8;
      ushort o[8];
#pragma unroll
      for (int j = 0; j < 8; j++) o[j] = Ts[(r8 + j) * 72 + oc];
      *(int4v*)(WoT + (size_t)(ct + oc) * 1024 + rt + r8) = *(const int4v*)o;
    }
  } else {
    const int w = t >> 6, lane = t & 63;
    const int row = (bid - 6400) * 4 + w;
    float s = 0.f;
#pragma unroll
    for (int i = 0; i < 4; i++) {
      const int j = i * 256 + lane * 4;
      float4v wv = *(const float4v*)(Wd + (size_t)row * 1024 + j);
      float4v bv = *(const float4v*)(bo + j);
      s += wv.x * bv.x + wv.y * bv.y + wv.z * bv.z + wv.w * bv.w;
    }
#pragma unroll
    for (int off = 1; off <= 32; off <<= 1) s += __shfl_xor(s, off);
    if (lane == 0) bc[row] = s + bd[row];
    if (row < 4 && lane == 1) dep[row] = 1.0f / 2048.0f;  // softmax rows sum to 1
  }
}

// ---------------------------------------------------------------------------
// Generic GEMM (fallback Wc path): C = A @ W^T, bf16 out. 128x128, BK=32.
// ---------------------------------------------------------------------------
__global__ __launch_bounds__(256, 2)
void gemm_bt(const ushort* __restrict__ A, const ushort* __restrict__ W,
             ushort* __restrict__ C, int K) {
  __shared__ ushort As[128 * 32];
  __shared__ ushort Bs[128 * 32];
  const int t = threadIdx.x;
  const int w = t >> 6;
  const int lane = t & 63;
  const int m16 = lane & 15, quad = lane >> 4;
  const int bx = blockIdx.x, by = blockIdx.y;
  const int warpRow = w >> 1, warpCol = w & 1;

  const int srow = t >> 2;
  const int scol = (t & 3) * 8;
  const ushort* Aptr = A + (size_t)(by * 128) * K;
  const ushort* Wptr = W + (size_t)(bx * 128) * K;

  float4v zero4 = {0.f, 0.f, 0.f, 0.f};
  float4v acc[4][4];
#pragma unroll
  for (int i = 0; i < 4; i++)
#pragma unroll
    for (int j = 0; j < 4; j++) acc[i][j] = zero4;

  for (int k0 = 0; k0 < K; k0 += 32) {
    __syncthreads();
#pragma unroll
    for (int r = 0; r < 2; r++) {
      const ushort* g = Aptr + (size_t)(r * 64 + srow) * K + (k0 + scol);
      __builtin_amdgcn_global_load_lds(
          (const __attribute__((address_space(1))) void*)g,
          (__attribute__((address_space(3))) void*)(As + r * 2048 + t * 8),
          16, 0, 0);
    }
#pragma unroll
    for (int r = 0; r < 2; r++) {
      const ushort* g = Wptr + (size_t)(r * 64 + srow) * K + (k0 + scol);
      __builtin_amdgcn_global_load_lds(
          (const __attribute__((address_space(1))) void*)g,
          (__attribute__((address_space(3))) void*)(Bs + r * 2048 + t * 8),
          16, 0, 0);
    }
    __syncthreads();

    short8 af[4], bf[4];
#pragma unroll
    for (int i = 0; i < 4; i++) {
      af[i] = *(const short8*)(As + (warpRow * 64 + i * 16 + m16) * 32 + quad * 8);
      bf[i] = *(const short8*)(Bs + (warpCol * 64 + i * 16 + m16) * 32 + quad * 8);
    }
#pragma unroll
    for (int i = 0; i < 4; i++)
#pragma unroll
      for (int j = 0; j < 4; j++)
        acc[i][j] = __builtin_amdgcn_mfma_f32_16x16x32_bf16(af[i], bf[j],
                                                            acc[i][j], 0, 0, 0);
  }

  const int crow_base = by * 128 + warpRow * 64;
  const int ccol_base = bx * 128 + warpCol * 64;
#pragma unroll
  for (int j = 0; j < 4; j++) {
    const int col = ccol_base + j * 16 + m16;
#pragma unroll
    for (int i = 0; i < 4; i++) {
      const int row = crow_base + i * 16 + quad * 4;
#pragma unroll
      for (int r = 0; r < 4; r++)
        C[(size_t)(row + r) * 1024 + col] = f2bf(acc[i][j][r]);
    }
  }
}

// ---------------------------------------------------------------------------
// Fused QKV GEMM, XCD-swizzled. Blocks < 1536: qkv = Xb @ Wib^T + bi.
//   - bx < 16 : Q,K columns -> qkv (bf16, stride 3072)
//   - bx >= 16: V columns   -> Vt transposed + zero-shuffle key permutation
// Blocks >= 1536 (merged mode): Wc = A2 @ W2^T (bf16) -> C2.
// ---------------------------------------------------------------------------
__global__ __launch_bounds__(256, 2)
void gemm_qkv(const ushort* __restrict__ Xb, const ushort* __restrict__ Wib,
              const float* __restrict__ bi, ushort* __restrict__ qkv,
              ushort* __restrict__ Vt,
              const ushort* __restrict__ A2, const ushort* __restrict__ W2,
              ushort* __restrict__ C2) {
  __shared__ ushort As[128 * 32];
  __shared__ ushort Bs[128 * 32];
  const int t = threadIdx.x;
  const int w = t >> 6;
  const int lane = t & 63;
  const int m16 = lane & 15, quad = lane >> 4;
  const int bid = blockIdx.x;
  const bool second = bid >= 1536;
  int bx, by;
  const ushort *A, *W;
  if (!second) {
    const int swz = (bid & 7) * 192 + (bid >> 3);   // XCD-contiguous panels
    bx = swz % 24; by = swz / 24; A = Xb; W = Wib;
  } else {
    const int b2 = bid - 1536; bx = b2 & 7; by = b2 >> 3; A = A2; W = W2;
  }
  const int warpRow = w >> 1, warpCol = w & 1;
  const int K = 1024;

  const int srow = t >> 2;
  const int scol = (t & 3) * 8;
  const ushort* Aptr = A + (size_t)(by * 128) * K;
  const ushort* Wptr = W + (size_t)(bx * 128) * K;

  float4v zero4 = {0.f, 0.f, 0.f, 0.f};
  float4v acc[4][4];
#pragma unroll
  for (int i = 0; i < 4; i++)
#pragma unroll
    for (int j = 0; j < 4; j++) acc[i][j] = zero4;

  for (int k0 = 0; k0 < K; k0 += 32) {
    __syncthreads();
#pragma unroll
    for (int r = 0; r < 2; r++) {
      const ushort* g = Aptr + (size_t)(r * 64 + srow) * K + (k0 + scol);
      __builtin_amdgcn_global_load_lds(
          (const __attribute__((address_space(1))) void*)g,
          (__attribute__((address_space(3))) void*)(As + r * 2048 + t * 8),
          16, 0, 0);
    }
#pragma unroll
    for (int r = 0; r < 2; r++) {
      const ushort* g = Wptr + (size_t)(r * 64 + srow) * K + (k0 + scol);
      __builtin_amdgcn_global_load_lds(
          (const __attribute__((address_space(1))) void*)g,
          (__attribute__((address_space(3))) void*)(Bs + r * 2048 + t * 8),
          16, 0, 0);
    }
    __syncthreads();

    short8 af[4], bf[4];
#pragma unroll
    for (int i = 0; i < 4; i++) {
      af[i] = *(const short8*)(As + (warpRow * 64 + i * 16 + m16) * 32 + quad * 8);
      bf[i] = *(const short8*)(Bs + (warpCol * 64 + i * 16 + m16) * 32 + quad * 8);
    }
#pragma unroll
    for (int i = 0; i < 4; i++)
#pragma unroll
      for (int j = 0; j < 4; j++)
        acc[i][j] = __builtin_amdgcn_mfma_f32_16x16x32_bf16(af[i], bf[j],
                                                            acc[i][j], 0, 0, 0);
  }

  const int crow_base = by * 128 + warpRow * 64;
  const int ccol_base = bx * 128 + warpCol * 64;

  if (second) {
#pragma unroll
    for (int j = 0; j < 4; j++) {
      const int col = ccol_base + j * 16 + m16;
#pragma unroll
      for (int i = 0; i < 4; i++) {
        const int row = crow_base + i * 16 + quad * 4;
#pragma unroll
        for (int r = 0; r < 4; r++)
          C2[(size_t)(row + r) * 1024 + col] = f2bf(acc[i][j][r]);
      }
    }
  } else if (bx < 16) {
#pragma unroll
    for (int j = 0; j < 4; j++) {
      const int col = ccol_base + j * 16 + m16;
      const float bv = bi[col];
#pragma unroll
      for (int i = 0; i < 4; i++) {
        const int row = crow_base + i * 16 + quad * 4;
#pragma unroll
        for (int r = 0; r < 4; r++)
          qkv[(size_t)(row + r) * 3072 + col] = f2bf(acc[i][j][r] + bv);
      }
    }
  } else {
    // V columns -> Vt transposed + key-permuted.
    const int b = by >> 4;
#pragma unroll
    for (int j = 0; j < 4; j++) {
      const int col = ccol_base + j * 16 + m16;   // 2048..3071
      const float bv = bi[col];
      const int vcol = col - 2048;
      const int h = vcol >> 7, d = vcol & 127;
      ushort* vrow = Vt + (size_t)((b * 8 + h) * 128 + d) * 2048;
#pragma unroll
      for (int i = 0; i < 4; i++) {
        const int pos = ((by & 15) << 7) + warpRow * 64 + ((i >> 1) << 5) +
                        (2 * quad + (i & 1)) * 4;
        uint2v o;
        o.x = cvtpk(acc[i][j][0] + bv, acc[i][j][1] + bv);
        o.y = cvtpk(acc[i][j][2] + bv, acc[i][j][3] + bv);
        *(uint2v*)(vrow + pos) = o;
      }
    }
  }
}

// ---------------------------------------------------------------------------
// Flash attention (R5 structure, best measured 96.6us + XCD decode).
// 256 thr = 4 waves, 32 q/wave, 128 q/block; 1-D grid 512, 2 blocks/CU.
// XCD-grouped decode (block->XCD = id%8): XCD x owns (h,b) pairs 4x..4x+3,
// 16 qt-blocks each -> K/V (4MB/XCD) L2-resident [FETCH 139->25MB, R6].
// S^T = K.Q^T, lane-local softmax, zero-shuffle PV (Vt key-permuted).
// KVBLK=32, 4-deep LDS ring (4 x (8KB K + 8KB V) = 64KB), prefetch
// distance 2, counted s_waitcnt vmcnt (4 loads/thr/tile -> 8 steady) +
// raw s_barrier: loads never drain to 0 inside the loop (T3/T4).
// Ring safety: stage(kt+2) overwrites buf (kt-2)&3; all waves passed
// barrier(kt-1) (ds_reads of kt-2 complete) before any stage(kt+2).
// ---------------------------------------------------------------------------
__global__ __launch_bounds__(256, 2)
void attn(const ushort* __restrict__ qkv, const ushort* __restrict__ Vt,
          ushort* __restrict__ ctx) {
  __shared__ ushort Ks[4][32 * 128];   // [key][d-chunk swizzled], 8KB/buf
  __shared__ ushort Vsm[4][128 * 32];  // [d][key-chunk swizzled], 8KB/buf
  const int t = threadIdx.x, w = t >> 6, lane = t & 63;
  const int m16 = lane & 15, quad = lane >> 4;
  const int i = blockIdx.x;
  const int x = i & 7, r0 = i >> 3;          // x = XCD
  const int pair = x * 4 + (r0 >> 4);        // 4 (h,b) pairs per XCD
  const int qt = r0 & 15;                    // 16 qt-blocks per pair
  const int h = pair & 7, b = pair >> 3;
  const int E3 = 3072;
  const size_t bbase = (size_t)b * 2048;

  const ushort* Qg = qkv + (bbase + qt * 128 + w * 32) * E3 + h * 128;
  const ushort* Kg = qkv + bbase * E3 + 1024 + h * 128;
  const ushort* Vg = Vt + (size_t)((b * 8 + h) * 128) * 2048;

  // 4 global_load_lds per thread per tile (2 K + 2 V).
  auto stage = [&](int kt, int buf) {
#pragma unroll
    for (int it = 0; it < 2; it++) {                 // K: 32 keys x 128 d
      const int c = it * 256 + t;
      const int row = c >> 4, cir = c & 15;
      const int j = (cir & 8) | ((cir ^ row) & 7);   // swizzled source chunk
      const ushort* g = Kg + (size_t)(kt * 32 + row) * E3 + j * 8;
      __builtin_amdgcn_global_load_lds(
          (const __attribute__((address_space(1))) void*)g,
          (__attribute__((address_space(3))) void*)(&Ks[buf][c * 8]), 16, 0, 0);
    }
#pragma unroll
    for (int it = 0; it < 2; it++) {                 // V^T: 128 d x 32 keys
      const int c = it * 256 + t;
      const int d = c >> 2, cir = c & 3;
      const int j = cir ^ ((d >> 1) & 3);            // 2-way-free read swizzle
      const ushort* g = Vg + (size_t)d * 2048 + kt * 32 + j * 8;
      __builtin_amdgcn_global_load_lds(
          (const __attribute__((address_space(1))) void*)g,
          (__attribute__((address_space(3))) void*)(&Vsm[buf][c * 8]), 16, 0, 0);
    }
  };

  stage(0, 0);
  stage(1, 1);

  const float c1 = 0.08838834764831845f * 1.4426950408889634f;  // scale*log2e
  // Q B-frags (n=m16 query, k=quad*8+j), pre-scaled by c1.
  short8 qf[2][4];
#pragma unroll
  for (int g = 0; g < 2; g++)
#pragma unroll
    for (int ks = 0; ks < 4; ks++) {
      short8 raw = *(const short8*)(Qg + (size_t)(g * 16 + m16) * E3 + ks * 32 + quad * 8);
      short8 s;
#pragma unroll
      for (int j = 0; j < 8; j++) s[j] = (short)f2bf(bf2f((ushort)raw[j]) * c1);
      qf[g][ks] = s;
    }

  // Per-lane swizzled chunk slots (row-low bits match staging swizzle).
  int kslot[4];
#pragma unroll
  for (int ks = 0; ks < 4; ks++) {
    const int j = ks * 4 + quad;
    kslot[ks] = (j & 8) | ((j ^ m16) & 7);
  }
  const int vslot = quad ^ ((m16 >> 1) & 3);

  float4v zero4 = {0.f, 0.f, 0.f, 0.f};
  float4v Oacc[2][8];
#pragma unroll
  for (int g = 0; g < 2; g++)
#pragma unroll
    for (int dt = 0; dt < 8; dt++) Oacc[g][dt] = zero4;
  float lsum[2] = {0.f, 0.f};

  for (int kt = 0; kt < 64; kt++) {
    if (kt < 62) {
      stage(kt + 2, (kt + 2) & 3);
      asm volatile("s_waitcnt vmcnt(8)" ::: "memory");  // tiles kt+1,kt+2 in flight
    } else if (kt == 62) {
      asm volatile("s_waitcnt vmcnt(4)" ::: "memory");  // tile 63 in flight
    } else {
      asm volatile("s_waitcnt vmcnt(0)" ::: "memory");
    }
    __builtin_amdgcn_s_barrier();
    __builtin_amdgcn_sched_barrier(0);   // fence: no LDS reads hoisted above
    const ushort* Ksb = Ks[kt & 3];
    const ushort* Vsb = Vsm[kt & 3];

    // ---- QK^T: 16 MFMA, 8 K-frag reads ----
    float4v st[2][2];  // [g][mt2: key-16-group]
    st[0][0] = zero4; st[0][1] = zero4; st[1][0] = zero4; st[1][1] = zero4;
    __builtin_amdgcn_s_setprio(1);
#pragma unroll
    for (int ks = 0; ks < 4; ks++) {
#pragma unroll
      for (int mt2 = 0; mt2 < 2; mt2++) {
        short8 kf = *(const short8*)(Ksb + (mt2 * 16 + m16) * 128 + kslot[ks] * 8);
        st[0][mt2] = __builtin_amdgcn_mfma_f32_16x16x32_bf16(kf, qf[0][ks], st[0][mt2], 0, 0, 0);
        st[1][mt2] = __builtin_amdgcn_mfma_f32_16x16x32_bf16(kf, qf[1][ks], st[1][mt2], 0, 0, 0);
      }
    }
    __builtin_amdgcn_s_setprio(0);

    // ---- softmax (lane-local; this tile's keys live in this lane) ----
    short8 pfr[2];
#pragma unroll
    for (int g = 0; g < 2; g++) {
      unsigned pk[4];
#pragma unroll
      for (int mt2 = 0; mt2 < 2; mt2++) {
        float p0 = __builtin_exp2f(st[g][mt2][0]);
        float p1 = __builtin_exp2f(st[g][mt2][1]);
        float p2 = __builtin_exp2f(st[g][mt2][2]);
        float p3 = __builtin_exp2f(st[g][mt2][3]);
        lsum[g] += (p0 + p1) + (p2 + p3);
        pk[mt2 * 2]     = cvtpk(p0, p1);
        pk[mt2 * 2 + 1] = cvtpk(p2, p3);
      }
      union { int4v iv; short8 s; } pf;
      pf.iv.x = (int)pk[0];
      pf.iv.y = (int)pk[1];
      pf.iv.z = (int)pk[2];
      pf.iv.w = (int)pk[3];
      pfr[g] = pf.s;
    }

    // ---- PV: 16 MFMA, 8 V-frag reads ----
    __builtin_amdgcn_s_setprio(1);
#pragma unroll
    for (int dt = 0; dt < 8; dt++) {
      short8 vf = *(const short8*)(Vsb + (dt * 16 + m16) * 32 + vslot * 8);
      Oacc[0][dt] = __builtin_amdgcn_mfma_f32_16x16x32_bf16(pfr[0], vf, Oacc[0][dt], 0, 0, 0);
      Oacc[1][dt] = __builtin_amdgcn_mfma_f32_16x16x32_bf16(pfr[1], vf, Oacc[1][dt], 0, 0, 0);
    }
    __builtin_amdgcn_s_setprio(0);
  }

  // Epilogue: reduce l across quads (query = m16), transpose via per-wave
  // scratch in Ks[0] (ring fully drained; wave-internal DS only).
#pragma unroll
  for (int g = 0; g < 2; g++) {
    float l = lsum[g];
    l += __shfl_xor(l, 16);
    l += __shfl_xor(l, 32);
    float* lf = (float*)(&Ks[0][w * 64]);
    lf[m16] = l;
    float linv[4];
#pragma unroll
    for (int r = 0; r < 4; r++) linv[r] = 1.0f / lf[quad * 4 + r];
#pragma unroll
    for (int r = 0; r < 4; r++) {
      const int row = qt * 128 + w * 32 + g * 16 + quad * 4 + r;
      ushort* crow = ctx + (bbase + row) * 1024 + h * 128;
#pragma unroll
      for (int dt = 0; dt < 8; dt++)
        crow[dt * 16 + m16] = f2bf(Oacc[g][dt][r] * linv[r]);
    }
  }
}

// ---------------------------------------------------------------------------
// Final GEMM: out = ctx[8192,1024] @ Wc[1024,1024]^T + bc, fp32 out.
// XCD-swizzled: per XCD 8 contiguous by-panels (2MB A, L2-resident).
// ---------------------------------------------------------------------------
__global__ __launch_bounds__(256, 2)
void gemm_fin(const ushort* __restrict__ A, const ushort* __restrict__ W,
              const float* __restrict__ bias, float* __restrict__ C) {
  __shared__ ushort As[128 * 32];
  __shared__ ushort Bs[128 * 32];
  const int t = threadIdx.x;
  const int w = t >> 6;
  const int lane = t & 63;
  const int m16 = lane & 15, quad = lane >> 4;
  const int swz = (blockIdx.x & 7) * 64 + (blockIdx.x >> 3);
  const int bx = swz & 7, by = swz >> 3;
  const int warpRow = w >> 1, warpCol = w & 1;
  const int K = 1024;

  const int srow = t >> 2;
  const int scol = (t & 3) * 8;
  const ushort* Aptr = A + (size_t)(by * 128) * K;
  const ushort* Wptr = W + (size_t)(bx * 128) * K;

  float4v zero4 = {0.f, 0.f, 0.f, 0.f};
  float4v acc[4][4];
#pragma unroll
  for (int i = 0; i < 4; i++)
#pragma unroll
    for (int j = 0; j < 4; j++) acc[i][j] = zero4;

  for (int k0 = 0; k0 < K; k0 += 32) {
    __syncthreads();
#pragma unroll
    for (int r = 0; r < 2; r++) {
      const ushort* g = Aptr + (size_t)(r * 64 + srow) * K + (k0 + scol);
      __builtin_amdgcn_global_load_lds(
          (const __attribute__((address_space(1))) void*)g,
          (__attribute__((address_space(3))) void*)(As + r * 2048 + t * 8),
          16, 0, 0);
    }
#pragma unroll
    for (int r = 0; r < 2; r++) {
      const ushort* g = Wptr + (size_t)(r * 64 + srow) * K + (k0 + scol);
      __builtin_amdgcn_global_load_lds(
          (const __attribute__((address_space(1))) void*)g,
          (__attribute__((address_space(3))) void*)(Bs + r * 2048 + t * 8),
          16, 0, 0);
    }
    __syncthreads();

    short8 af[4], bf[4];
#pragma unroll
    for (int i = 0; i < 4; i++) {
      af[i] = *(const short8*)(As + (warpRow * 64 + i * 16 + m16) * 32 + quad * 8);
      bf[i] = *(const short8*)(Bs + (warpCol * 64 + i * 16 + m16) * 32 + quad * 8);
    }
#pragma unroll
    for (int i = 0; i < 4; i++)
#pragma unroll
      for (int j = 0; j < 4; j++)
        acc[i][j] = __builtin_amdgcn_mfma_f32_16x16x32_bf16(af[i], bf[j],
                                                            acc[i][j], 0, 0, 0);
  }

  const int crow_base = by * 128 + warpRow * 64;
  const int ccol_base = bx * 128 + warpCol * 64;
#pragma unroll
  for (int j = 0; j < 4; j++) {
    const int col = ccol_base + j * 16 + m16;
    const float bv = bias[col];
#pragma unroll
    for (int i = 0; i < 4; i++) {
      const int row = crow_base + i * 16 + quad * 4;
#pragma unroll
      for (int r = 0; r < 4; r++)
        C[(size_t)(row + r) * 1024 + col] = acc[i][j][r] + bv;
    }
  }
}

extern "C" void kernel_launch(void* const* d_in, const int* in_sizes, int n_in,
                              void* d_out, int out_size, void* d_ws, size_t ws_size,
                              hipStream_t stream) {
  const float* X  = (const float*)d_in[0];
  const float* Wi = (const float*)d_in[1];
  const float* bi = (const float*)d_in[2];
  const float* Wo = (const float*)d_in[3];
  const float* bo = (const float*)d_in[4];
  const float* Wd = (const float*)d_in[5];
  const float* bd = (const float*)d_in[6];
  float* out = (float*)d_out;

  ushort* p    = (ushort*)d_ws;
  ushort* Xb   = p; p += (size_t)8192 * 1024;   // 16.8MB; ctx reuses (post-qkv)
  ushort* Wib  = p; p += (size_t)3072 * 1024;   //  6.3MB
  ushort* WoTb = p; p += (size_t)1024 * 1024;   //  2.1MB
  ushort* Wdb  = p; p += (size_t)1024 * 1024;   //  2.1MB
  ushort* qkv  = p; p += (size_t)8192 * 3072;   // 50.3MB (V cols unused)
  ushort* Vt   = p; p += (size_t)4096 * 2048;   // 16.8MB
  float*  bc   = (float*)p; p += 2048;          //  4KB
  ushort* WcbSep = p; p += (size_t)1024 * 1024; //  2.1MB (merged mode only)
  const size_t need_merged = (size_t)((char*)p - (char*)d_ws);
  const bool merged = ws_size >= need_merged;

  ushort* ctx = Xb;                     // free after qkv GEMM consumed Xb
  ushort* Wcb = merged ? WcbSep : Wib;  // fallback: alias (separate launch)

  prep<<<6656, 256, 0, stream>>>(X, Wi, Wd, Wo, bo, bd,
                                 Xb, Wib, Wdb, WoTb, bc, out);
  if (merged) {
    gemm_qkv<<<1600, 256, 0, stream>>>(Xb, Wib, bi, qkv, Vt, Wdb, WoTb, Wcb);
  } else {
    gemm_qkv<<<1536, 256, 0, stream>>>(Xb, Wib, bi, qkv, Vt, Wdb, WoTb, nullptr);
    gemm_bt<<<dim3(8, 8), 256, 0, stream>>>(Wdb, WoTb, Wcb, 1024);
  }
  attn<<<512, 256, 0, stream>>>(qkv, Vt, ctx);
  gemm_fin<<<512, 256, 0, stream>>>(ctx, Wcb, bc, out + 4);
}